// Round 3
// baseline (241.785 us; speedup 1.0000x reference)
//
#include <hip/hip_runtime.h>

// LengthRegulator: B=32, T=512, D=384, ML=4096 (fixed by setup_inputs).
// out[b,f,:] = (f < total_b) ? x[b, clip(searchsorted(cum_b, f, 'right'),0,T-1), :] : 0
// mel_pos[b,f] = (f < total_b) ? f+1 : 0  -- written as FLOAT values (d_out is
// read back as one flat float32 buffer).
//
// Round 3: same as round 2 but with clang ext_vector_type float4 so
// __builtin_nontemporal_store compiles (HIP's float4 is a class type the
// builtin rejects). Streaming stores keep x L2-resident for the ~3.5x gather
// reuse; divide-free index update; FPB=64 -> 2048 blocks = 8/CU.

typedef float v4f __attribute__((ext_vector_type(4)));

constexpr int B  = 32;
constexpr int T  = 512;
constexpr int D  = 384;
constexpr int ML = 4096;
constexpr int D4 = D / 4;                    // 96 float4 per row
constexpr int FPB = 64;                      // frames per block
constexpr int BLOCKS_PER_BATCH = ML / FPB;   // 64
constexpr int NT = 256;                      // threads per block
constexpr int ITERS = FPB * D4 / NT;         // 24 float4 stores per thread

__global__ __launch_bounds__(NT) void lr_kernel(
        const v4f* __restrict__ x,         // [B, T, D4]
        const int* __restrict__ dur,       // [B, T]
        v4f*       __restrict__ out4,      // [B, ML, D4]
        float*     __restrict__ mel)       // [B, ML]
{
    __shared__ int s_cum[T];
    __shared__ int s_tok[FPB];
    __shared__ int s_part[NT];

    const int b      = blockIdx.x / BLOCKS_PER_BATCH;
    const int fchunk = blockIdx.x % BLOCKS_PER_BATCH;
    const int f0     = fchunk * FPB;
    const int tid    = threadIdx.x;

    // ---- cumsum(duration[b]) into LDS (each thread owns 2 elements) ----
    const int d0 = dur[b * T + 2 * tid];
    const int d1 = dur[b * T + 2 * tid + 1];
    const int pair = d0 + d1;
    s_part[tid] = pair;
    __syncthreads();
    int val = pair;
    #pragma unroll
    for (int off = 1; off < NT; off <<= 1) {
        int t = (tid >= off) ? s_part[tid - off] : 0;
        __syncthreads();
        val += t;
        s_part[tid] = val;
        __syncthreads();
    }
    const int excl = val - pair;          // exclusive scan of pair-sums
    s_cum[2 * tid]     = excl + d0;
    s_cum[2 * tid + 1] = excl + pair;
    __syncthreads();
    const int total = s_cum[T - 1];

    const v4f zero4 = (v4f){0.f, 0.f, 0.f, 0.f};
    v4f* op = out4 + ((size_t)b * ML + f0) * D4 + tid;

    // Fully-invalid chunk: pure zero streaming, no search, no gather.
    if (f0 >= total) {
        if (tid < FPB) mel[b * ML + f0 + tid] = 0.0f;
        #pragma unroll
        for (int k = 0; k < ITERS; ++k) {
            __builtin_nontemporal_store(zero4, op);
            op += NT;
        }
        return;
    }

    // ---- token index for this block's FPB frames (binary search in LDS) ----
    if (tid < FPB) {
        const int f = f0 + tid;
        int lo = 0, hi = T;               // searchsorted(side='right')
        while (lo < hi) {
            const int mid = (lo + hi) >> 1;
            if (s_cum[mid] <= f) lo = mid + 1; else hi = mid;
        }
        const int tok = (lo < T - 1) ? lo : (T - 1);
        s_tok[tid] = (f < total) ? tok : -1;
        mel[b * ML + f] = (f < total) ? (float)(f + 1) : 0.0f;
    }
    __syncthreads();

    // ---- coalesced float4 copy: FPB*D4 = 6144 vec4 per block ----
    const v4f* xb = x + (size_t)b * T * D4;
    int i  = tid;
    int lf = i / D4;                      // one divide, then incremental
    int c  = i - lf * D4;
    #pragma unroll
    for (int k = 0; k < ITERS; ++k) {
        const int tok = s_tok[lf];
        v4f v = zero4;
        if (tok >= 0) v = xb[tok * D4 + c];
        __builtin_nontemporal_store(v, op);
        op += NT;
        lf += 2; c += NT - 2 * D4;        // advance linear index by NT=256
        if (c >= D4) { c -= D4; ++lf; }
    }
}

extern "C" void kernel_launch(void* const* d_in, const int* in_sizes, int n_in,
                              void* d_out, int out_size, void* d_ws, size_t ws_size,
                              hipStream_t stream) {
    const v4f* x    = (const v4f*)d_in[0];
    const int* dur  = (const int*)d_in[1];
    float* outf = (float*)d_out;
    float* mel  = outf + (size_t)B * ML * D;   // mel_pos region, float values

    dim3 grid(B * BLOCKS_PER_BATCH);
    dim3 block(NT);
    lr_kernel<<<grid, block, 0, stream>>>(x, dur, (v4f*)outf, mel);
}

// Round 4
// 232.890 us; speedup vs baseline: 1.0382x; 1.0382x over previous
//
#include <hip/hip_runtime.h>

// LengthRegulator: B=32, T=512, D=384, ML=4096 (fixed by setup_inputs).
// out[b,f,:] = (f < total_b) ? x[b, clip(searchsorted(cum_b, f, 'right'),0,T-1), :] : 0
// mel_pos[b,f] = (f < total_b) ? f+1 : 0  -- written as FLOAT values (d_out is
// read back as one flat float32 buffer).
//
// Round 4: XCD-aware swizzle — map blockIdx so each XCD (assumed round-robin
// blockIdx%8) owns 4 whole batches: per-XCD x working set = 3.1 MB < 4 MiB L2.
// Nontemporal output stores bypass L2 so x stays resident for the ~3.5x reuse.

typedef float v4f __attribute__((ext_vector_type(4)));

constexpr int B  = 32;
constexpr int T  = 512;
constexpr int D  = 384;
constexpr int ML = 4096;
constexpr int D4 = D / 4;                    // 96 float4 per row
constexpr int FPB = 64;                      // frames per block
constexpr int BLOCKS_PER_BATCH = ML / FPB;   // 64
constexpr int NT = 256;                      // threads per block
constexpr int ITERS = FPB * D4 / NT;         // 24 float4 stores per thread
constexpr int NXCD = 8;
constexpr int BATCHES_PER_XCD = B / NXCD;    // 4

__global__ __launch_bounds__(NT) void lr_kernel(
        const v4f* __restrict__ x,         // [B, T, D4]
        const int* __restrict__ dur,       // [B, T]
        v4f*       __restrict__ out4,      // [B, ML, D4]
        float*     __restrict__ mel)       // [B, ML]
{
    __shared__ int s_cum[T];
    __shared__ int s_tok[FPB];
    __shared__ int s_part[NT];

    // XCD-locality swizzle: xcd = i&7 (HW round-robin heuristic; perf-only).
    // Each XCD gets batches {xcd, xcd+8, xcd+16, xcd+24}, all 64 chunks each.
    const int i_blk   = blockIdx.x;
    const int xcd     = i_blk & (NXCD - 1);
    const int j       = i_blk >> 3;                      // [0, 256)
    const int b       = xcd + NXCD * (j >> 6);           // [0, 32)
    const int fchunk  = j & (BLOCKS_PER_BATCH - 1);      // [0, 64)
    const int f0      = fchunk * FPB;
    const int tid     = threadIdx.x;

    // ---- cumsum(duration[b]) into LDS (each thread owns 2 elements) ----
    const int d0 = dur[b * T + 2 * tid];
    const int d1 = dur[b * T + 2 * tid + 1];
    const int pair = d0 + d1;
    s_part[tid] = pair;
    __syncthreads();
    int val = pair;
    #pragma unroll
    for (int off = 1; off < NT; off <<= 1) {
        int t = (tid >= off) ? s_part[tid - off] : 0;
        __syncthreads();
        val += t;
        s_part[tid] = val;
        __syncthreads();
    }
    const int excl = val - pair;          // exclusive scan of pair-sums
    s_cum[2 * tid]     = excl + d0;
    s_cum[2 * tid + 1] = excl + pair;
    __syncthreads();
    const int total = s_cum[T - 1];

    const v4f zero4 = (v4f){0.f, 0.f, 0.f, 0.f};
    v4f* op = out4 + ((size_t)b * ML + f0) * D4 + tid;

    // Fully-invalid chunk: pure zero streaming, no search, no gather.
    if (f0 >= total) {
        if (tid < FPB) mel[b * ML + f0 + tid] = 0.0f;
        #pragma unroll
        for (int k = 0; k < ITERS; ++k) {
            __builtin_nontemporal_store(zero4, op);
            op += NT;
        }
        return;
    }

    // ---- token index for this block's FPB frames (binary search in LDS) ----
    if (tid < FPB) {
        const int f = f0 + tid;
        int lo = 0, hi = T;               // searchsorted(side='right')
        while (lo < hi) {
            const int mid = (lo + hi) >> 1;
            if (s_cum[mid] <= f) lo = mid + 1; else hi = mid;
        }
        const int tok = (lo < T - 1) ? lo : (T - 1);
        s_tok[tid] = (f < total) ? tok : -1;
        mel[b * ML + f] = (f < total) ? (float)(f + 1) : 0.0f;
    }
    __syncthreads();

    // ---- coalesced float4 copy: FPB*D4 = 6144 vec4 per block ----
    const v4f* xb = x + (size_t)b * T * D4;
    int i  = tid;
    int lf = i / D4;                      // one divide, then incremental
    int c  = i - lf * D4;
    #pragma unroll
    for (int k = 0; k < ITERS; ++k) {
        const int tok = s_tok[lf];
        v4f v = zero4;
        if (tok >= 0) v = xb[tok * D4 + c];
        __builtin_nontemporal_store(v, op);
        op += NT;
        lf += 2; c += NT - 2 * D4;        // advance linear index by NT=256
        if (c >= D4) { c -= D4; ++lf; }
    }
}

extern "C" void kernel_launch(void* const* d_in, const int* in_sizes, int n_in,
                              void* d_out, int out_size, void* d_ws, size_t ws_size,
                              hipStream_t stream) {
    const v4f* x    = (const v4f*)d_in[0];
    const int* dur  = (const int*)d_in[1];
    float* outf = (float*)d_out;
    float* mel  = outf + (size_t)B * ML * D;   // mel_pos region, float values

    dim3 grid(B * BLOCKS_PER_BATCH);
    dim3 block(NT);
    lr_kernel<<<grid, block, 0, stream>>>(x, dur, (v4f*)outf, mel);
}